// Round 5
// baseline (330.843 us; speedup 1.0000x reference)
//
#include <hip/hip_runtime.h>
#include <math.h>

#define N_TOKENS 32768
#define DIM      4096
#define NE       64
#define KQ       4
#define KSPAN    (DIM / KQ)             // 1024
#define NBLK_MAIN (N_TOKENS / 32)       // 1024 blocks, 4 waves each (wave = K-quarter)
#define NBLK_POST (N_TOKENS / 256)      // 128
#define EPS_GAP  2e-3f
#define REFINE_BLOCKS 1024

// d_out layout (float32 elements):
//   [0, 65536)        weights  [N_TOKENS][2]
//   [65536, 131072)   indices  [N_TOKENS][2]  stored as float
//   [131072, 131136)  new_bias [64]
//
// d_ws layout (4-byte units):
//   [0, 64)              ews_refine[64]  (float, zeroed per call)
//   [64]                 worklist count  (uint, zeroed per call)
//   [128, 8320)          per-post-block expert partials [128][64] (float)
//   [16384, 49152)       worklist token ids (int)
//   [65664, 327808)      W fragments: whi then wlo (bf16, 512KB each)
//   [524288, 8912896)    partial scores psc[4][N_TOKENS][64] (f32, 33.5MB)
#define WOFF     65664
#define WL_OFF   16384
#define PART_OFF 128
#define PSC_OFF  524288
#define WFRAG_ELEMS (512 * 512)   // 262144 bf16 per plane

typedef __bf16 bf16x8 __attribute__((ext_vector_type(8)));
typedef float  f32x16 __attribute__((ext_vector_type(16)));

// Convert W [64][4096] f32 -> fragment-ordered bf16 hi/lo.
// Fragment f = K16*2 + nt:  element (f, lane, b) =
//   W[nt*32 + (lane&31)][K16*16 + (lane>>5)*8 + b]
__global__ __launch_bounds__(256) void prep_w(
    const float* __restrict__ w, float* __restrict__ ws)
{
    __bf16* whi = (__bf16*)(ws + WOFF);
    __bf16* wlo = whi + WFRAG_ELEMS;
    const int tid  = blockIdx.x * 256 + threadIdx.x;  // 0..32767
    const int f    = tid >> 6, lane = tid & 63;
    const int nt   = f & 1,    K16  = f >> 1;
    const int e    = nt * 32 + (lane & 31);
    const int k    = K16 * 16 + (lane >> 5) * 8;
    const float4 a = *(const float4*)(w + (size_t)e * DIM + k);
    const float4 b = *(const float4*)(w + (size_t)e * DIM + k + 4);
    const float v[8] = {a.x, a.y, a.z, a.w, b.x, b.y, b.z, b.w};
    __bf16 h[8], l[8];
    #pragma unroll
    for (int i = 0; i < 8; ++i) {
        h[i] = (__bf16)v[i];
        l[i] = (__bf16)(v[i] - (float)h[i]);
    }
    *(bf16x8*)(whi + (size_t)tid * 8) = *(bf16x8*)h;
    *(bf16x8*)(wlo + (size_t)tid * 8) = *(bf16x8*)l;
}

// ---- f32 -> bf16 hi/lo via truncation bit-ops (residual ~2^-16 rel) ----
__device__ __forceinline__ unsigned pack_pair(float f0, float f1, float& r0, float& r1) {
    const unsigned u0 = __float_as_uint(f0), u1 = __float_as_uint(f1);
    const unsigned h0 = u0 & 0xFFFF0000u,   h1 = u1 & 0xFFFF0000u;
    r0 = f0 - __uint_as_float(h0);
    r1 = f1 - __uint_as_float(h1);
    return (u0 >> 16) | h1;
}
__device__ __forceinline__ void cvt8(const float4 a, const float4 b, uint4& h, uint4& l) {
    float r0, r1, r2, r3, r4, r5, r6, r7;
    h.x = pack_pair(a.x, a.y, r0, r1);
    h.y = pack_pair(a.z, a.w, r2, r3);
    h.z = pack_pair(b.x, b.y, r4, r5);
    h.w = pack_pair(b.z, b.w, r6, r7);
    l.x = (__float_as_uint(r0) >> 16) | (__float_as_uint(r1) & 0xFFFF0000u);
    l.y = (__float_as_uint(r2) >> 16) | (__float_as_uint(r3) & 0xFFFF0000u);
    l.z = (__float_as_uint(r4) >> 16) | (__float_as_uint(r5) & 0xFFFF0000u);
    l.w = (__float_as_uint(r6) >> 16) | (__float_as_uint(r7) & 0xFFFF0000u);
}

struct Bset { bf16x8 h[2][2]; bf16x8 l[2][2]; };   // [kstep][nt]

__device__ __forceinline__ void loadB(Bset& B, const __bf16* whi, const __bf16* wlo,
                                      int k16, int lane) {
    #pragma unroll
    for (int s = 0; s < 2; ++s)
        #pragma unroll
        for (int nt = 0; nt < 2; ++nt) {
            const size_t idx = ((size_t)((k16 + s) * 2 + nt) * 64 + lane) * 8;
            B.h[s][nt] = *(const bf16x8*)(whi + idx);
            B.l[s][nt] = *(const bf16x8*)(wlo + idx);
        }
}

__device__ __forceinline__ void mma_k32(const uint4 h0, const uint4 l0,
                                        const uint4 h1, const uint4 l1,
                                        const Bset& B, f32x16& acc0, f32x16& acc1) {
    const bf16x8 ah0 = __builtin_bit_cast(bf16x8, h0);
    const bf16x8 al0 = __builtin_bit_cast(bf16x8, l0);
    const bf16x8 ah1 = __builtin_bit_cast(bf16x8, h1);
    const bf16x8 al1 = __builtin_bit_cast(bf16x8, l1);
    acc0 = __builtin_amdgcn_mfma_f32_32x32x16_bf16(ah0, B.h[0][0], acc0, 0, 0, 0);
    acc1 = __builtin_amdgcn_mfma_f32_32x32x16_bf16(ah0, B.h[0][1], acc1, 0, 0, 0);
    acc0 = __builtin_amdgcn_mfma_f32_32x32x16_bf16(al0, B.h[0][0], acc0, 0, 0, 0);
    acc1 = __builtin_amdgcn_mfma_f32_32x32x16_bf16(al0, B.h[0][1], acc1, 0, 0, 0);
    acc0 = __builtin_amdgcn_mfma_f32_32x32x16_bf16(ah0, B.l[0][0], acc0, 0, 0, 0);
    acc1 = __builtin_amdgcn_mfma_f32_32x32x16_bf16(ah0, B.l[0][1], acc1, 0, 0, 0);
    acc0 = __builtin_amdgcn_mfma_f32_32x32x16_bf16(ah1, B.h[1][0], acc0, 0, 0, 0);
    acc1 = __builtin_amdgcn_mfma_f32_32x32x16_bf16(ah1, B.h[1][1], acc1, 0, 0, 0);
    acc0 = __builtin_amdgcn_mfma_f32_32x32x16_bf16(al1, B.h[1][0], acc0, 0, 0, 0);
    acc1 = __builtin_amdgcn_mfma_f32_32x32x16_bf16(al1, B.h[1][1], acc1, 0, 0, 0);
    acc0 = __builtin_amdgcn_mfma_f32_32x32x16_bf16(ah1, B.l[1][0], acc0, 0, 0, 0);
    acc1 = __builtin_amdgcn_mfma_f32_32x32x16_bf16(ah1, B.l[1][1], acc1, 0, 0, 0);
}

// Barrier-free streaming GEMM. Block = 32 tokens; wave w = K-quarter w.
// Writes psc[kq][tok][e].
__global__ __launch_bounds__(256) void gate_main(
    const float* __restrict__ x, float* __restrict__ ws)
{
    const __bf16* whi = (const __bf16*)(ws + WOFF);
    const __bf16* wlo = whi + WFRAG_ELEMS;
    float*        psc = ws + PSC_OFF;

    const int t    = threadIdx.x;
    const int lane = t & 63;
    const int wv   = t >> 6;             // K-quarter
    const int tb   = blockIdx.x * 32;
    const int kbeg = wv * KSPAN;
    const int kend = kbeg + KSPAN;

    const int row = tb + (lane & 31);
    const int kh8 = (lane >> 5) * 8;     // k-half float offset within a k-step
    const float* xr = x + (size_t)row * DIM;

    f32x16 acc0, acc1;
    #pragma unroll
    for (int i = 0; i < 16; ++i) { acc0[i] = 0.f; acc1[i] = 0.f; }

    float4 xA0, xA1, xA2, xA3, xB0, xB1, xB2, xB3;
    Bset BA, BB;
    uint4 h0, l0, h1, l1;

    #define LOADX(P0, P1, P2, P3, kc)                         \
        P0 = *(const float4*)(xr + (kc) + kh8);               \
        P1 = *(const float4*)(xr + (kc) + kh8 + 4);           \
        P2 = *(const float4*)(xr + (kc) + 16 + kh8);          \
        P3 = *(const float4*)(xr + (kc) + 16 + kh8 + 4);

    // prologue: xA, BA, xB (so first MFMA's wait on BA never drains xB)
    LOADX(xA0, xA1, xA2, xA3, kbeg);
    loadB(BA, whi, wlo, kbeg >> 4, lane);
    LOADX(xB0, xB1, xB2, xB3, kbeg + 32);

    for (int s = 0; s < KSPAN / 64; ++s) {     // 16 double-iters
        const int kc = kbeg + s * 64;

        // ---- half A: compute k32 at kc ----
        loadB(BB, whi, wlo, (kc + 32) >> 4, lane);          // (1) B prefetch (always in range)
        cvt8(xA0, xA1, h0, l0);                             // (2) waits only oldest x
        cvt8(xA2, xA3, h1, l1);
        { const int kn = (kc + 64 < kend) ? kc + 64 : kbeg; // (3) x prefetch, depth 2
          LOADX(xA0, xA1, xA2, xA3, kn); }
        mma_k32(h0, l0, h1, l1, BA, acc0, acc1);            // (4) waits BA (older than x prefetches)

        // ---- half B: compute k32 at kc+32 ----
        { const int k16n = (kc + 64 < kend) ? (kc + 64) >> 4 : kbeg >> 4;
          loadB(BA, whi, wlo, k16n, lane); }
        cvt8(xB0, xB1, h0, l0);
        cvt8(xB2, xB3, h1, l1);
        { const int kn = (kc + 96 < kend) ? kc + 96 : kbeg;
          LOADX(xB0, xB1, xB2, xB3, kn); }
        mma_k32(h0, l0, h1, l1, BB, acc0, acc1);
    }
    #undef LOADX

    // C/D layout: col = lane&31 (expert), row = (r&3)+8*(r>>2)+4*(lane>>5) (token)
    const int e0 = lane & 31;
    const int rsel = 4 * (lane >> 5);
    float* p = psc + ((size_t)wv * N_TOKENS + tb) * NE;
    #pragma unroll
    for (int r = 0; r < 16; ++r) {
        const int tok = (r & 3) + 8 * (r >> 2) + rsel;
        p[(size_t)tok * NE + e0]      = acc0[r];
        p[(size_t)tok * NE + e0 + 32] = acc1[r];
    }
}

// Sum 4 K-quarters + bias, top-3 scan, risky-flag or write outputs; expert partials.
__global__ __launch_bounds__(256) void gate_post(
    const float* __restrict__ bias,
    float* __restrict__ out,
    float* __restrict__ ws)
{
    __shared__ float sbias[NE];
    __shared__ float part[NE];
    unsigned* wl_count = (unsigned*)(ws + 64);
    float*    partials = ws + PART_OFF;
    int*      wl       = (int*)(ws + WL_OFF);
    const float* psc   = ws + PSC_OFF;
    const size_t PL    = (size_t)N_TOKENS * NE;

    const int t = threadIdx.x;
    if (t < NE) { sbias[t] = bias[t]; part[t] = 0.f; }
    __syncthreads();

    const int tok = blockIdx.x * 256 + t;
    const float* p = psc + (size_t)tok * NE;

    float v1 = -3e38f, v2 = -3e38f, v3 = -3e38f;
    int   i1 = 0,      i2 = 0;
    #pragma unroll
    for (int g = 0; g < 16; ++g) {
        const float4 a = *(const float4*)(p + g * 4);
        const float4 b = *(const float4*)(p + PL + g * 4);
        const float4 c = *(const float4*)(p + 2 * PL + g * 4);
        const float4 d = *(const float4*)(p + 3 * PL + g * 4);
        float sv4[4] = {(a.x + b.x) + (c.x + d.x), (a.y + b.y) + (c.y + d.y),
                        (a.z + b.z) + (c.z + d.z), (a.w + b.w) + (c.w + d.w)};
        #pragma unroll
        for (int j = 0; j < 4; ++j) {
            const float sv = sv4[j] + sbias[g * 4 + j];
            const int   e  = g * 4 + j;
            if (sv > v1)      { v3 = v2; v2 = v1; i2 = i1; v1 = sv; i1 = e; }
            else if (sv > v2) { v3 = v2; v2 = sv; i2 = e; }
            else if (sv > v3) { v3 = sv; }
        }
    }
    const bool risky = (v1 - v2 < EPS_GAP) || (v2 - v3 < EPS_GAP);
    if (risky) {
        const int pos = (int)atomicAdd(wl_count, 1u);
        wl[pos] = tok;                       // refined later in fp64
    } else {
        const float ex = expf(v2 - v1);      // <= 1
        const float w1 = 1.f / (1.f + ex);
        const float w2 = ex * w1;
        const size_t g = (size_t)tok * 2;
        *(float2*)(out + g)                        = make_float2(w1, w2);
        *(float2*)(out + (size_t)N_TOKENS * 2 + g) = make_float2((float)i1, (float)i2);
        atomicAdd(&part[i1], w1);
        atomicAdd(&part[i2], w2);
    }
    __syncthreads();
    if (t < NE) partials[(size_t)blockIdx.x * NE + t] = part[t];
}

// fp64 re-score of near-tie tokens: exact ordering vs the true scores.
__global__ __launch_bounds__(256) void gate_refine(
    const float* __restrict__ x,
    const float* __restrict__ w,
    const float* __restrict__ bias,
    float* __restrict__ out,
    float* __restrict__ ws)
{
    float*          ews_ref  = ws;
    const unsigned* wl_count = (const unsigned*)(ws + 64);
    const int*      wl       = (const int*)(ws + WL_OFF);

    const int t = threadIdx.x;
    const int e = t >> 2;        // expert 0..63
    const int q = t & 3;         // quarter of K
    __shared__ double sc[NE];

    const unsigned count = *wl_count;
    for (unsigned it = blockIdx.x; it < count; it += gridDim.x) {
        const int tok = wl[it];
        const float* xr = x + (size_t)tok * DIM;
        const float* wr = w + (size_t)e * DIM;
        double s = 0.0;
        const int k0 = q * (DIM / 4), k1 = k0 + DIM / 4;
        for (int k = k0; k < k1; k += 4) {
            const float4 a = *(const float4*)(xr + k);
            const float4 b = *(const float4*)(wr + k);
            s += (double)a.x * (double)b.x;
            s += (double)a.y * (double)b.y;
            s += (double)a.z * (double)b.z;
            s += (double)a.w * (double)b.w;
        }
        s += __shfl_xor(s, 1);
        s += __shfl_xor(s, 2);
        if (q == 0) sc[e] = s + (double)bias[e];
        __syncthreads();

        if (t == 0) {
            double v1 = -1e300, v2 = -1e300;
            int i1 = 0, i2 = 0;
            for (int j = 0; j < NE; ++j) {
                const double sv = sc[j];
                if (sv > v1)      { v2 = v1; i2 = i1; v1 = sv; i1 = j; }
                else if (sv > v2) { v2 = sv; i2 = j; }
            }
            const double ex = exp(v2 - v1);
            const double w1 = 1.0 / (1.0 + ex);
            const double w2 = ex * w1;
            const size_t g = (size_t)tok * 2;
            *(float2*)(out + g)                        = make_float2((float)w1, (float)w2);
            *(float2*)(out + (size_t)N_TOKENS * 2 + g) = make_float2((float)i1, (float)i2);
            atomicAdd(&ews_ref[i1], (float)w1);
            atomicAdd(&ews_ref[i2], (float)w2);
        }
        __syncthreads();
    }
}

__global__ void gate_bias(
    const float* __restrict__ bias,
    const float* __restrict__ target,
    const float* __restrict__ ws,
    float* __restrict__ out)
{
    const int e = threadIdx.x;   // 64 threads, one wave
    const float* partials = ws + PART_OFF;
    float v = ws[e];             // refined-token contribution
    for (int b = 0; b < NBLK_POST; ++b) v += partials[(size_t)b * NE + e];
    float total = v;
    #pragma unroll
    for (int off = 32; off > 0; off >>= 1)
        total += __shfl_xor(total, off);
    const float nb = bias[e] + 0.001f * ((target[e] * total - v) / total);
    out[(size_t)N_TOKENS * 4 + e] = nb;
}

extern "C" void kernel_launch(void* const* d_in, const int* in_sizes, int n_in,
                              void* d_out, int out_size, void* d_ws, size_t ws_size,
                              hipStream_t stream) {
    const float* x      = (const float*)d_in[0];
    const float* w      = (const float*)d_in[1];
    const float* bias   = (const float*)d_in[2];
    const float* target = (const float*)d_in[3];
    float* out = (float*)d_out;
    float* ws  = (float*)d_ws;

    hipMemsetAsync(ws, 0, 128 * sizeof(float), stream);   // ews_ref + wl_count
    prep_w     <<<128, 256, 0, stream>>>(w, ws);
    gate_main  <<<NBLK_MAIN, 256, 0, stream>>>(x, ws);
    gate_post  <<<NBLK_POST, 256, 0, stream>>>(bias, out, ws);
    gate_refine<<<REFINE_BLOCKS, 256, 0, stream>>>(x, w, bias, out, ws);
    gate_bias  <<<1, 64, 0, stream>>>(bias, target, ws, out);
}

// Round 6
// 298.066 us; speedup vs baseline: 1.1100x; 1.1100x over previous
//
#include <hip/hip_runtime.h>
#include <math.h>

#define N_TOKENS 32768
#define DIM      4096
#define NE       64
#define TM       64              // tokens per block
#define BK       128             // K-chunk (floats)
#define KHALF    (DIM / 2)       // 2048
#define NBLK_MAIN (N_TOKENS / TM * 2)   // 1024 (x2 for K-split)
#define NBLK_POST (N_TOKENS / 256)      // 128
#define EPS_GAP  2e-3f
#define REFINE_BLOCKS 1024

// d_out layout (float32 elements):
//   [0, 65536)        weights  [N_TOKENS][2]
//   [65536, 131072)   indices  [N_TOKENS][2]  stored as float
//   [131072, 131136)  new_bias [64]
//
// d_ws layout (4-byte units):
//   [0, 64)              ews_refine[64]  (float, zeroed per call)
//   [64]                 worklist count  (uint, zeroed per call)
//   [128, 8320)          per-post-block expert partials [128][64] (float)
//   [16384, 49152)       worklist token ids (int)
//   [65664, 327808)      W fragments: whi then wlo (bf16, 512KB each)
//   [524288, 4718592)    partial scores psc[2][N_TOKENS][64] (f32, 16.8MB)
#define WOFF     65664
#define WL_OFF   16384
#define PART_OFF 128
#define PSC_OFF  524288
#define WFRAG_ELEMS (512 * 512)   // 262144 bf16 per plane

typedef __bf16 bf16x8 __attribute__((ext_vector_type(8)));
typedef float  f32x16 __attribute__((ext_vector_type(16)));

// Convert W [64][4096] f32 -> fragment-ordered bf16 hi/lo.
// Fragment f = K16*2 + nt:  element (f, lane, b) =
//   W[nt*32 + (lane&31)][K16*16 + (lane>>5)*8 + b]
__global__ __launch_bounds__(256) void prep_w(
    const float* __restrict__ w, float* __restrict__ ws)
{
    __bf16* whi = (__bf16*)(ws + WOFF);
    __bf16* wlo = whi + WFRAG_ELEMS;
    const int tid  = blockIdx.x * 256 + threadIdx.x;  // 0..32767
    const int f    = tid >> 6, lane = tid & 63;
    const int nt   = f & 1,    K16  = f >> 1;
    const int e    = nt * 32 + (lane & 31);
    const int k    = K16 * 16 + (lane >> 5) * 8;
    const float4 a = *(const float4*)(w + (size_t)e * DIM + k);
    const float4 b = *(const float4*)(w + (size_t)e * DIM + k + 4);
    const float v[8] = {a.x, a.y, a.z, a.w, b.x, b.y, b.z, b.w};
    __bf16 h[8], l[8];
    #pragma unroll
    for (int i = 0; i < 8; ++i) {
        h[i] = (__bf16)v[i];
        l[i] = (__bf16)(v[i] - (float)h[i]);
    }
    *(bf16x8*)(whi + (size_t)tid * 8) = *(bf16x8*)h;
    *(bf16x8*)(wlo + (size_t)tid * 8) = *(bf16x8*)l;
}

// ---- f32 -> bf16 hi/lo via truncation bit-ops (residual ~2^-16 rel) ----
__device__ __forceinline__ unsigned pack_pair(float f0, float f1, float& r0, float& r1) {
    const unsigned u0 = __float_as_uint(f0), u1 = __float_as_uint(f1);
    const unsigned h0 = u0 & 0xFFFF0000u,   h1 = u1 & 0xFFFF0000u;
    r0 = f0 - __uint_as_float(h0);
    r1 = f1 - __uint_as_float(h1);
    return (u0 >> 16) | h1;
}
__device__ __forceinline__ void cvt8(const float4 a, const float4 b, uint4& h, uint4& l) {
    float r0, r1, r2, r3, r4, r5, r6, r7;
    h.x = pack_pair(a.x, a.y, r0, r1);
    h.y = pack_pair(a.z, a.w, r2, r3);
    h.z = pack_pair(b.x, b.y, r4, r5);
    h.w = pack_pair(b.z, b.w, r6, r7);
    l.x = (__float_as_uint(r0) >> 16) | (__float_as_uint(r1) & 0xFFFF0000u);
    l.y = (__float_as_uint(r2) >> 16) | (__float_as_uint(r3) & 0xFFFF0000u);
    l.z = (__float_as_uint(r4) >> 16) | (__float_as_uint(r5) & 0xFFFF0000u);
    l.w = (__float_as_uint(r6) >> 16) | (__float_as_uint(r7) & 0xFFFF0000u);
}

// async global->LDS, 16B per lane; lds base must be wave-uniform.
__device__ __forceinline__ void gload_lds16(const float* g, float* lds) {
    __builtin_amdgcn_global_load_lds(
        (const __attribute__((address_space(1))) unsigned*)g,
        (__attribute__((address_space(3))) unsigned*)lds, 16, 0, 0);
}

// m97-style split-K GEMM: block b = tokens [tb,tb+64) x K-half (b&1).
// x staged f32 via global_load_lds, 16B-slot swizzle col^(row&31) applied on
// the GLOBAL source (LDS dest linear); bf16 hi/lo conversion at frag read.
__global__ __launch_bounds__(256) void gate_main(
    const float* __restrict__ x, float* __restrict__ ws)
{
    __shared__ __align__(16) float xs[TM * BK];   // 32KB: row=token (512B), swizzled 16B slots

    const __bf16* whi = (const __bf16*)(ws + WOFF);
    const __bf16* wlo = whi + WFRAG_ELEMS;
    float*        psc = ws + PSC_OFF;

    const int t    = threadIdx.x;
    const int lane = t & 63;
    const int wave = t >> 6;
    const int mt   = wave >> 1;          // token half (0/1)
    const int nt   = wave & 1;           // expert half (0/1)
    const int kh   = blockIdx.x & 1;     // K half
    const int tb   = (blockIdx.x >> 1) * TM;
    const int kbeg = kh * KHALF;

    const int l31 = lane & 31, lhi = lane >> 5;

    // staging per-lane source offsets (element units), one per wave-load.
    // wave-load wl covers LDS rows R0=wave*16+2*wl, R0+1 (1KB linear dest).
    // lane l writes stored slot (l&31) of row R0+(l>>5); content must be
    // logical slot (l&31)^(row&31)  ->  pre-swizzled global column.
    size_t sbase[8];
    #pragma unroll
    for (int wl = 0; wl < 8; ++wl) {
        const int row = wave * 16 + wl * 2 + lhi;
        const int col = l31 ^ (row & 31);            // 16B slot within chunk
        sbase[wl] = (size_t)(tb + row) * DIM + kbeg + col * 4;
    }

    const int a_row = mt * 32 + l31;                 // token row this lane reads

    f32x16 acc0, acc12;
    #pragma unroll
    for (int i = 0; i < 16; ++i) { acc0[i] = 0.f; acc12[i] = 0.f; }

    for (int s = 0; s < KHALF / BK; ++s) {           // 16 chunks
        // ---- async stage x chunk into LDS ----
        #pragma unroll
        for (int wl = 0; wl < 8; ++wl)
            gload_lds16(x + sbase[wl] + s * BK, &xs[(wave * 16 + wl * 2) * BK]);
        __syncthreads();                             // drains vmcnt(0)

        // ---- compute: 8 k16 steps, cvt at read, 3 MFMA each ----
        const int K16c = (kbeg + s * BK) >> 4;
        #pragma unroll
        for (int ks = 0; ks < 8; ++ks) {
            const int s0 = ks * 4 + (lhi << 1);      // logical 16B slot
            const float4 fa = *(const float4*)&xs[a_row * BK + ((s0 ^ l31) << 2)];
            const float4 fb = *(const float4*)&xs[a_row * BK + (((s0 + 1) ^ l31) << 2)];
            uint4 h, l;
            cvt8(fa, fb, h, l);
            const size_t bidx = ((size_t)((K16c + ks) * 2 + nt) * 64 + lane) * 8;
            const bf16x8 bh = *(const bf16x8*)(whi + bidx);
            const bf16x8 bl = *(const bf16x8*)(wlo + bidx);
            const bf16x8 ah = __builtin_bit_cast(bf16x8, h);
            const bf16x8 al = __builtin_bit_cast(bf16x8, l);
            acc0  = __builtin_amdgcn_mfma_f32_32x32x16_bf16(ah, bh, acc0,  0, 0, 0);
            acc12 = __builtin_amdgcn_mfma_f32_32x32x16_bf16(al, bh, acc12, 0, 0, 0);
            acc12 = __builtin_amdgcn_mfma_f32_32x32x16_bf16(ah, bl, acc12, 0, 0, 0);
        }
        __syncthreads();                             // before next overwrite
    }

    // C/D layout: col = lane&31 (expert), row = (r&3)+8*(r>>2)+4*(lane>>5)
    float* p = psc + (size_t)kh * N_TOKENS * NE + (size_t)tb * NE;
    #pragma unroll
    for (int r = 0; r < 16; ++r) {
        const int tok = mt * 32 + (r & 3) + 8 * (r >> 2) + 4 * lhi;
        p[(size_t)tok * NE + nt * 32 + l31] = acc0[r] + acc12[r];
    }
}

// Sum K-halves + bias, top-3 scan, risky-flag or write outputs; expert partials.
__global__ __launch_bounds__(256) void gate_post(
    const float* __restrict__ bias,
    float* __restrict__ out,
    float* __restrict__ ws)
{
    __shared__ float sbias[NE];
    __shared__ float part[NE];
    unsigned* wl_count = (unsigned*)(ws + 64);
    float*    partials = ws + PART_OFF;
    int*      wl       = (int*)(ws + WL_OFF);
    const float* psc   = ws + PSC_OFF;
    const size_t PL    = (size_t)N_TOKENS * NE;

    const int t = threadIdx.x;
    if (t < NE) { sbias[t] = bias[t]; part[t] = 0.f; }
    __syncthreads();

    const int tok = blockIdx.x * 256 + t;
    const float* p = psc + (size_t)tok * NE;

    float v1 = -3e38f, v2 = -3e38f, v3 = -3e38f;
    int   i1 = 0,      i2 = 0;
    #pragma unroll
    for (int g = 0; g < 16; ++g) {
        const float4 a = *(const float4*)(p + g * 4);
        const float4 b = *(const float4*)(p + PL + g * 4);
        float sv4[4] = {a.x + b.x, a.y + b.y, a.z + b.z, a.w + b.w};
        #pragma unroll
        for (int j = 0; j < 4; ++j) {
            const float sv = sv4[j] + sbias[g * 4 + j];
            const int   e  = g * 4 + j;
            if (sv > v1)      { v3 = v2; v2 = v1; i2 = i1; v1 = sv; i1 = e; }
            else if (sv > v2) { v3 = v2; v2 = sv; i2 = e; }
            else if (sv > v3) { v3 = sv; }
        }
    }
    const bool risky = (v1 - v2 < EPS_GAP) || (v2 - v3 < EPS_GAP);
    if (risky) {
        const int pos = (int)atomicAdd(wl_count, 1u);
        wl[pos] = tok;                       // refined later in fp64
    } else {
        const float ex = expf(v2 - v1);      // <= 1
        const float w1 = 1.f / (1.f + ex);
        const float w2 = ex * w1;
        const size_t g = (size_t)tok * 2;
        *(float2*)(out + g)                        = make_float2(w1, w2);
        *(float2*)(out + (size_t)N_TOKENS * 2 + g) = make_float2((float)i1, (float)i2);
        atomicAdd(&part[i1], w1);
        atomicAdd(&part[i2], w2);
    }
    __syncthreads();
    if (t < NE) partials[(size_t)blockIdx.x * NE + t] = part[t];
}

// fp64 re-score of near-tie tokens: exact ordering vs the true scores.
__global__ __launch_bounds__(256) void gate_refine(
    const float* __restrict__ x,
    const float* __restrict__ w,
    const float* __restrict__ bias,
    float* __restrict__ out,
    float* __restrict__ ws)
{
    float*          ews_ref  = ws;
    const unsigned* wl_count = (const unsigned*)(ws + 64);
    const int*      wl       = (const int*)(ws + WL_OFF);

    const int t = threadIdx.x;
    const int e = t >> 2;        // expert 0..63
    const int q = t & 3;         // quarter of K
    __shared__ double sc[NE];

    const unsigned count = *wl_count;
    for (unsigned it = blockIdx.x; it < count; it += gridDim.x) {
        const int tok = wl[it];
        const float* xr = x + (size_t)tok * DIM;
        const float* wr = w + (size_t)e * DIM;
        double s = 0.0;
        const int k0 = q * (DIM / 4), k1 = k0 + DIM / 4;
        for (int k = k0; k < k1; k += 4) {
            const float4 a = *(const float4*)(xr + k);
            const float4 b = *(const float4*)(wr + k);
            s += (double)a.x * (double)b.x;
            s += (double)a.y * (double)b.y;
            s += (double)a.z * (double)b.z;
            s += (double)a.w * (double)b.w;
        }
        s += __shfl_xor(s, 1);
        s += __shfl_xor(s, 2);
        if (q == 0) sc[e] = s + (double)bias[e];
        __syncthreads();

        if (t == 0) {
            double v1 = -1e300, v2 = -1e300;
            int i1 = 0, i2 = 0;
            for (int j = 0; j < NE; ++j) {
                const double sv = sc[j];
                if (sv > v1)      { v2 = v1; i2 = i1; v1 = sv; i1 = j; }
                else if (sv > v2) { v2 = sv; i2 = j; }
            }
            const double ex = exp(v2 - v1);
            const double w1 = 1.0 / (1.0 + ex);
            const double w2 = ex * w1;
            const size_t g = (size_t)tok * 2;
            *(float2*)(out + g)                        = make_float2((float)w1, (float)w2);
            *(float2*)(out + (size_t)N_TOKENS * 2 + g) = make_float2((float)i1, (float)i2);
            atomicAdd(&ews_ref[i1], (float)w1);
            atomicAdd(&ews_ref[i2], (float)w2);
        }
        __syncthreads();
    }
}

__global__ void gate_bias(
    const float* __restrict__ bias,
    const float* __restrict__ target,
    const float* __restrict__ ws,
    float* __restrict__ out)
{
    const int e = threadIdx.x;   // 64 threads, one wave
    const float* partials = ws + PART_OFF;
    float v = ws[e];             // refined-token contribution
    for (int b = 0; b < NBLK_POST; ++b) v += partials[(size_t)b * NE + e];
    float total = v;
    #pragma unroll
    for (int off = 32; off > 0; off >>= 1)
        total += __shfl_xor(total, off);
    const float nb = bias[e] + 0.001f * ((target[e] * total - v) / total);
    out[(size_t)N_TOKENS * 4 + e] = nb;
}

extern "C" void kernel_launch(void* const* d_in, const int* in_sizes, int n_in,
                              void* d_out, int out_size, void* d_ws, size_t ws_size,
                              hipStream_t stream) {
    const float* x      = (const float*)d_in[0];
    const float* w      = (const float*)d_in[1];
    const float* bias   = (const float*)d_in[2];
    const float* target = (const float*)d_in[3];
    float* out = (float*)d_out;
    float* ws  = (float*)d_ws;

    hipMemsetAsync(ws, 0, 128 * sizeof(float), stream);   // ews_ref + wl_count
    prep_w     <<<128, 256, 0, stream>>>(w, ws);
    gate_main  <<<NBLK_MAIN, 256, 0, stream>>>(x, ws);
    gate_post  <<<NBLK_POST, 256, 0, stream>>>(bias, out, ws);
    gate_refine<<<REFINE_BLOCKS, 256, 0, stream>>>(x, w, bias, out, ws);
    gate_bias  <<<1, 64, 0, stream>>>(bias, target, ws, out);
}